// Round 4
// baseline (382.079 us; speedup 1.0000x reference)
//
#include <hip/hip_runtime.h>

#define TT 100
#define BB 2048
#define NI 3
#define NU 128
#define NB 256
#define NPC 256
#define NHD 12

typedef __attribute__((ext_vector_type(8))) short short8;
typedef __attribute__((ext_vector_type(4))) float f32x4;

__device__ __forceinline__ float fast_sigmoid(float x) {
  return 1.0f / (1.0f + __expf(-x));
}
__device__ __forceinline__ float fast_tanh(float x) {
  return 1.0f - 2.0f / (__expf(2.0f * x) + 1.0f);
}
__device__ __forceinline__ short f2bf(float f) {
  uint32_t u = __float_as_uint(f);
  u += 0x7FFF + ((u >> 16) & 1);  // RNE
  return (short)(u >> 16);
}
__device__ __forceinline__ float bf2f(short s) {
  return __uint_as_float(((uint32_t)(uint16_t)s) << 16);
}
// LDS-only barrier: leaves global (vmcnt) ops in flight across the barrier.
// All cross-wave traffic in the GRU loop is LDS -> lgkmcnt(0) suffices.
__device__ __forceinline__ void lds_barrier() {
  asm volatile("s_waitcnt lgkmcnt(0)" ::: "memory");
  __builtin_amdgcn_s_barrier();
}

// ---------------------------------------------------------------------------
// h0 = concat(init_pc, init_hd) @ W_embed + b_embed     [B, NU]
// ---------------------------------------------------------------------------
__global__ __launch_bounds__(256) void embed_kernel(
    const float* __restrict__ init_pc, const float* __restrict__ init_hd,
    const float* __restrict__ W_embed, const float* __restrict__ b_embed,
    float* __restrict__ h0) {
  __shared__ float pcs[2][NPC];
  __shared__ float hds[2][NHD];
  const int tid = threadIdx.x;
  const int b0 = blockIdx.x * 2;

  for (int idx = tid; idx < 2 * NPC; idx += 256)
    pcs[idx >> 8][idx & 255] =
        init_pc[(size_t)(b0 + (idx >> 8)) * NPC + (idx & 255)];
  if (tid < 2 * NHD) {
    int rr = tid / NHD, cc = tid - rr * NHD;
    hds[rr][cc] = init_hd[(size_t)(b0 + rr) * NHD + cc];
  }
  __syncthreads();

  const int half = tid >> 7;
  const int j = tid & 127;
  const float* Wp = W_embed + j;
  float a0 = 0.f, a1 = 0.f, a2 = 0.f, a3 = 0.f;
#pragma unroll 4
  for (int k = 0; k < NPC; k += 4) {
    a0 = fmaf(pcs[half][k + 0], Wp[(k + 0) * NU], a0);
    a1 = fmaf(pcs[half][k + 1], Wp[(k + 1) * NU], a1);
    a2 = fmaf(pcs[half][k + 2], Wp[(k + 2) * NU], a2);
    a3 = fmaf(pcs[half][k + 3], Wp[(k + 3) * NU], a3);
  }
#pragma unroll
  for (int k = 0; k < NHD; ++k)
    a0 = fmaf(hds[half][k], Wp[(NPC + k) * NU], a0);
  float acc = b_embed[j] + ((a0 + a1) + (a2 + a3));
  h0[(size_t)(b0 + half) * NU + j] = acc;
}

// ---------------------------------------------------------------------------
// MFMA GRU scan, latency-optimized.
// 256 blocks x 8 rows, 512 thr = 8 waves; wave w owns cols 16w..16w+15.
// U in VGPRs (hi/lo bf16 B-frags). h master in D-layout regs.
// Phase A: r-gate (12 MFMA, 2 chains) -> rh planes -> lds_barrier.
// Phase B: z + h-tilde (24 MFMA, 4 chains) -> h planes -> lds_barrier
//          -> states store (left in flight; no vmcnt drain in loop).
// x for all 100 steps preloaded to LDS (no global loads in loop).
// ---------------------------------------------------------------------------
__global__ __launch_bounds__(512, 2) void gru_mfma_kernel(
    const float* __restrict__ x, const float* __restrict__ h0,
    const float* __restrict__ Wz, const float* __restrict__ Wr,
    const float* __restrict__ Wh, const float* __restrict__ Uz,
    const float* __restrict__ Ur, const float* __restrict__ Uh,
    const float* __restrict__ bz, const float* __restrict__ br,
    const float* __restrict__ bh, float* __restrict__ states,
    float* __restrict__ final_state) {
  __shared__ short h_hi[16 * 128];
  __shared__ short h_lo[16 * 128];
  __shared__ short p_hi[16 * 128];
  __shared__ short p_lo[16 * 128];
  __shared__ float xs[TT][8][4];

  const int tid = threadIdx.x;
  const int lane = tid & 63;
  const int w = tid >> 6;
  const int ln15 = lane & 15;
  const int g4 = lane >> 4;
  const int col = w * 16 + ln15;
  const int row0 = blockIdx.x * 8;

  // ---- preload x slice for all T: xs[t][r][i] (i=3 pad) ----
  for (int idx = tid; idx < TT * 32; idx += 512) {
    const int t = idx >> 5, rem = idx & 31, r = rem >> 2, i = rem & 3;
    xs[t][r][i] = (i < 3) ? x[(size_t)(t * BB + row0 + r) * NI + i] : 0.0f;
  }

  // per-lane input-projection weights (column slice)
  const float wz0 = Wz[col], wz1 = Wz[NU + col], wz2 = Wz[2 * NU + col];
  const float wr0 = Wr[col], wr1 = Wr[NU + col], wr2 = Wr[2 * NU + col];
  const float wh0 = Wh[col], wh1 = Wh[NU + col], wh2 = Wh[2 * NU + col];
  const float bzv = bz[col], brv = br[col], bhv = bh[col];

  // U B-fragments, hi/lo split
  short8 Uzh[4], Uzl[4], Urh[4], Url[4], Uhh[4], Uhl[4];
#pragma unroll
  for (int kt = 0; kt < 4; ++kt) {
#pragma unroll
    for (int e = 0; e < 8; ++e) {
      const int kk = kt * 32 + g4 * 8 + e;
      float v;
      short hi;
      v = Uz[kk * NU + col];
      hi = f2bf(v);
      Uzh[kt][e] = hi;
      Uzl[kt][e] = f2bf(v - bf2f(hi));
      v = Ur[kk * NU + col];
      hi = f2bf(v);
      Urh[kt][e] = hi;
      Url[kt][e] = f2bf(v - bf2f(hi));
      v = Uh[kk * NU + col];
      hi = f2bf(v);
      Uhh[kt][e] = hi;
      Uhl[kt][e] = f2bf(v - bf2f(hi));
    }
  }

  // init h regs + planes (pad rows 8-15 zeroed)
  float hreg[4];
#pragma unroll
  for (int q = 0; q < 4; ++q) {
    const int row = g4 * 4 + q;
    hreg[q] = (row < 8) ? h0[(size_t)(row0 + row) * NU + col] : 0.0f;
    const int off = row * 256 + ((col * 2) ^ ((row & 7) << 4));
    const short hi = f2bf(hreg[q]);
    *(short*)((char*)h_hi + off) = hi;
    *(short*)((char*)h_lo + off) = f2bf(hreg[q] - bf2f(hi));
  }
  __syncthreads();

  // precomputed fragment byte offsets
  int foff[4];
#pragma unroll
  for (int kt = 0; kt < 4; ++kt)
    foff[kt] = ln15 * 256 + ((kt * 64 + g4 * 16) ^ ((ln15 & 7) << 4));
  int woff[4];
#pragma unroll
  for (int q = 0; q < 4; ++q) {
    const int row = g4 * 4 + q;
    woff[q] = row * 256 + ((col * 2) ^ ((row & 7) << 4));
  }

  for (int t = 0; t < TT; ++t) {
    // ================= phase A: r gate =================
    short8 ahi[4], alo[4];
#pragma unroll
    for (int kt = 0; kt < 4; ++kt) {
      ahi[kt] = *(const short8*)((const char*)h_hi + foff[kt]);
      alo[kt] = *(const short8*)((const char*)h_lo + foff[kt]);
    }
    float4 xrow[4];
#pragma unroll
    for (int q = 0; q < 4; ++q)
      xrow[q] = *(const float4*)xs[t][(g4 * 4 + q) & 7];

    f32x4 r0, r1 = {0.f, 0.f, 0.f, 0.f};
#pragma unroll
    for (int q = 0; q < 4; ++q)
      r0[q] =
          fmaf(xrow[q].x, wr0, fmaf(xrow[q].y, wr1, fmaf(xrow[q].z, wr2, brv)));
    // two independent 6-deep chains (kt {0,2} -> r0, {1,3} -> r1)
    r0 = __builtin_amdgcn_mfma_f32_16x16x32_bf16(ahi[0], Urh[0], r0, 0, 0, 0);
    r1 = __builtin_amdgcn_mfma_f32_16x16x32_bf16(ahi[1], Urh[1], r1, 0, 0, 0);
    r0 = __builtin_amdgcn_mfma_f32_16x16x32_bf16(alo[0], Urh[0], r0, 0, 0, 0);
    r1 = __builtin_amdgcn_mfma_f32_16x16x32_bf16(alo[1], Urh[1], r1, 0, 0, 0);
    r0 = __builtin_amdgcn_mfma_f32_16x16x32_bf16(ahi[0], Url[0], r0, 0, 0, 0);
    r1 = __builtin_amdgcn_mfma_f32_16x16x32_bf16(ahi[1], Url[1], r1, 0, 0, 0);
    r0 = __builtin_amdgcn_mfma_f32_16x16x32_bf16(ahi[2], Urh[2], r0, 0, 0, 0);
    r1 = __builtin_amdgcn_mfma_f32_16x16x32_bf16(ahi[3], Urh[3], r1, 0, 0, 0);
    r0 = __builtin_amdgcn_mfma_f32_16x16x32_bf16(alo[2], Urh[2], r0, 0, 0, 0);
    r1 = __builtin_amdgcn_mfma_f32_16x16x32_bf16(alo[3], Urh[3], r1, 0, 0, 0);
    r0 = __builtin_amdgcn_mfma_f32_16x16x32_bf16(ahi[2], Url[2], r0, 0, 0, 0);
    r1 = __builtin_amdgcn_mfma_f32_16x16x32_bf16(ahi[3], Url[3], r1, 0, 0, 0);

    if (g4 < 2) {
#pragma unroll
      for (int q = 0; q < 4; ++q) {
        const float rh = fast_sigmoid(r0[q] + r1[q]) * hreg[q];
        const short hi = f2bf(rh);
        *(short*)((char*)p_hi + woff[q]) = hi;
        *(short*)((char*)p_lo + woff[q]) = f2bf(rh - bf2f(hi));
      }
    }
    lds_barrier();  // rh planes visible

    // ================= phase B: z + h-tilde =================
    short8 phi[4], plo[4];
#pragma unroll
    for (int kt = 0; kt < 4; ++kt) {
      phi[kt] = *(const short8*)((const char*)p_hi + foff[kt]);
      plo[kt] = *(const short8*)((const char*)p_lo + foff[kt]);
    }
    f32x4 z0, z1 = {0.f, 0.f, 0.f, 0.f};
    f32x4 hh0, hh1 = {0.f, 0.f, 0.f, 0.f};
#pragma unroll
    for (int q = 0; q < 4; ++q) {
      z0[q] =
          fmaf(xrow[q].x, wz0, fmaf(xrow[q].y, wz1, fmaf(xrow[q].z, wz2, bzv)));
      hh0[q] =
          fmaf(xrow[q].x, wh0, fmaf(xrow[q].y, wh1, fmaf(xrow[q].z, wh2, bhv)));
    }
    // four independent 6-deep chains
    z0 = __builtin_amdgcn_mfma_f32_16x16x32_bf16(ahi[0], Uzh[0], z0, 0, 0, 0);
    z1 = __builtin_amdgcn_mfma_f32_16x16x32_bf16(ahi[1], Uzh[1], z1, 0, 0, 0);
    hh0 = __builtin_amdgcn_mfma_f32_16x16x32_bf16(phi[0], Uhh[0], hh0, 0, 0, 0);
    hh1 = __builtin_amdgcn_mfma_f32_16x16x32_bf16(phi[1], Uhh[1], hh1, 0, 0, 0);
    z0 = __builtin_amdgcn_mfma_f32_16x16x32_bf16(alo[0], Uzh[0], z0, 0, 0, 0);
    z1 = __builtin_amdgcn_mfma_f32_16x16x32_bf16(alo[1], Uzh[1], z1, 0, 0, 0);
    hh0 = __builtin_amdgcn_mfma_f32_16x16x32_bf16(plo[0], Uhh[0], hh0, 0, 0, 0);
    hh1 = __builtin_amdgcn_mfma_f32_16x16x32_bf16(plo[1], Uhh[1], hh1, 0, 0, 0);
    z0 = __builtin_amdgcn_mfma_f32_16x16x32_bf16(ahi[0], Uzl[0], z0, 0, 0, 0);
    z1 = __builtin_amdgcn_mfma_f32_16x16x32_bf16(ahi[1], Uzl[1], z1, 0, 0, 0);
    hh0 = __builtin_amdgcn_mfma_f32_16x16x32_bf16(phi[0], Uhl[0], hh0, 0, 0, 0);
    hh1 = __builtin_amdgcn_mfma_f32_16x16x32_bf16(phi[1], Uhl[1], hh1, 0, 0, 0);
    z0 = __builtin_amdgcn_mfma_f32_16x16x32_bf16(ahi[2], Uzh[2], z0, 0, 0, 0);
    z1 = __builtin_amdgcn_mfma_f32_16x16x32_bf16(ahi[3], Uzh[3], z1, 0, 0, 0);
    hh0 = __builtin_amdgcn_mfma_f32_16x16x32_bf16(phi[2], Uhh[2], hh0, 0, 0, 0);
    hh1 = __builtin_amdgcn_mfma_f32_16x16x32_bf16(phi[3], Uhh[3], hh1, 0, 0, 0);
    z0 = __builtin_amdgcn_mfma_f32_16x16x32_bf16(alo[2], Uzh[2], z0, 0, 0, 0);
    z1 = __builtin_amdgcn_mfma_f32_16x16x32_bf16(alo[3], Uzh[3], z1, 0, 0, 0);
    hh0 = __builtin_amdgcn_mfma_f32_16x16x32_bf16(plo[2], Uhh[2], hh0, 0, 0, 0);
    hh1 = __builtin_amdgcn_mfma_f32_16x16x32_bf16(plo[3], Uhh[3], hh1, 0, 0, 0);
    z0 = __builtin_amdgcn_mfma_f32_16x16x32_bf16(ahi[2], Uzl[2], z0, 0, 0, 0);
    z1 = __builtin_amdgcn_mfma_f32_16x16x32_bf16(ahi[3], Uzl[3], z1, 0, 0, 0);
    hh0 = __builtin_amdgcn_mfma_f32_16x16x32_bf16(phi[2], Uhl[2], hh0, 0, 0, 0);
    hh1 = __builtin_amdgcn_mfma_f32_16x16x32_bf16(phi[3], Uhl[3], hh1, 0, 0, 0);

#pragma unroll
    for (int q = 0; q < 4; ++q) {
      const float zg = fast_sigmoid(z0[q] + z1[q]);
      const float htw = fast_tanh(hh0[q] + hh1[q]);
      hreg[q] = fmaf(zg, htw - hreg[q], hreg[q]);
    }
    if (g4 < 2) {
#pragma unroll
      for (int q = 0; q < 4; ++q) {
        const short hi = f2bf(hreg[q]);
        *(short*)((char*)h_hi + woff[q]) = hi;
        *(short*)((char*)h_lo + woff[q]) = f2bf(hreg[q] - bf2f(hi));
      }
    }
    lds_barrier();  // h planes visible
    // fire-and-forget HBM store, overlaps next step (no vmcnt wait in loop)
    if (g4 < 2) {
#pragma unroll
      for (int q = 0; q < 4; ++q)
        states[((size_t)t * BB + row0 + g4 * 4 + q) * NU + col] = hreg[q];
    }
  }

  if (g4 < 2) {
#pragma unroll
    for (int q = 0; q < 4; ++q)
      final_state[(size_t)(row0 + g4 * 4 + q) * NU + col] = hreg[q];
  }
}

// ---------------------------------------------------------------------------
// Pre-pack weights into bf16 MFMA B-fragment order.
// ---------------------------------------------------------------------------
__global__ __launch_bounds__(256) void prepack_kernel(
    const float* __restrict__ Wb, const float* __restrict__ Wpc,
    const float* __restrict__ Whd, short* __restrict__ Wb_pack,
    short* __restrict__ Wpc_pack, short* __restrict__ Whd_pack) {
  int t = blockIdx.x * 256 + threadIdx.x;
  if (t >= 200 * 64) return;
  int fb = t >> 6, lane = t & 63;
  const float* W;
  short* out;
  int n_tile, k_tile, N, local;
  if (fb < 64) {
    W = Wb; out = Wb_pack; local = fb; n_tile = fb >> 2; k_tile = fb & 3; N = 256;
  } else if (fb < 192) {
    int f = fb - 64;
    W = Wpc; out = Wpc_pack; local = f; n_tile = f >> 3; k_tile = f & 7; N = 256;
  } else {
    int f = fb - 192;
    W = Whd; out = Whd_pack; local = f; n_tile = 0; k_tile = f; N = 12;
  }
  short8 p;
#pragma unroll
  for (int e = 0; e < 8; ++e) {
    int k = k_tile * 32 + (lane >> 4) * 8 + e;
    int colc = n_tile * 16 + (lane & 15);
    float v = (colc < N) ? W[k * N + colc] : 0.0f;
    p[e] = f2bf(v);
  }
  *((short8*)out + (local * 64 + lane)) = p;
}

// ---------------------------------------------------------------------------
// MFMA heads: 64 rows/block, 256 threads (4 waves, 16-row stripe each).
// ---------------------------------------------------------------------------
__global__ __launch_bounds__(256, 3) void heads_mfma_kernel(
    const float* __restrict__ states, const short* __restrict__ Wb_pack,
    const short* __restrict__ Wpc_pack, const short* __restrict__ Whd_pack,
    const float* __restrict__ b_pc, const float* __restrict__ b_hd,
    float* __restrict__ out_hd, float* __restrict__ out_pc,
    float* __restrict__ out_bn) {
  __shared__ short s_lds[64 * 128];   // 16 KB
  __shared__ short bn_lds[64 * 256];  // 32 KB
  const int tid = threadIdx.x;
  const size_t R0 = (size_t)blockIdx.x * 64;

  for (int c = tid; c < 1024; c += 256) {
    int row = c >> 4, s16 = c & 15;
    const float* src = states + (R0 + row) * 128 + s16 * 8;
    float4 v0 = *(const float4*)src;
    float4 v1 = *(const float4*)(src + 4);
    short8 p;
    p[0] = f2bf(v0.x); p[1] = f2bf(v0.y); p[2] = f2bf(v0.z); p[3] = f2bf(v0.w);
    p[4] = f2bf(v1.x); p[5] = f2bf(v1.y); p[6] = f2bf(v1.z); p[7] = f2bf(v1.w);
    int byte = row * 256 + ((s16 * 16) ^ ((row & 7) << 4));
    *(short8*)((char*)s_lds + byte) = p;
  }
  __syncthreads();

  const int lane = tid & 63;
  const int wave = tid >> 6;
  const int ln15 = lane & 15;
  const int ln4 = lane >> 4;
  const int r0 = wave * 16;

  {
    short8 a[4];
#pragma unroll
    for (int kt = 0; kt < 4; ++kt) {
      int byte =
          (r0 + ln15) * 256 + ((kt * 64 + ln4 * 16) ^ ((ln15 & 7) << 4));
      a[kt] = *(const short8*)((const char*)s_lds + byte);
    }
#pragma unroll
    for (int nt = 0; nt < 16; ++nt) {
      f32x4 acc = {0.f, 0.f, 0.f, 0.f};
      const short8* bp = (const short8*)Wb_pack + (nt * 4) * 64 + lane;
#pragma unroll
      for (int kt = 0; kt < 4; ++kt)
        acc = __builtin_amdgcn_mfma_f32_16x16x32_bf16(a[kt], bp[kt * 64], acc,
                                                      0, 0, 0);
      int colc = nt * 16 + ln15;
#pragma unroll
      for (int q = 0; q < 4; ++q) {
        int row = r0 + ln4 * 4 + q;
        out_bn[(R0 + row) * NB + colc] = acc[q];
        int byte = row * 512 + ((colc * 2) ^ ((row & 7) << 4));
        *(short*)((char*)bn_lds + byte) = f2bf(acc[q]);
      }
    }
  }
  __syncthreads();

  {
    short8 ab[8];
#pragma unroll
    for (int kt = 0; kt < 8; ++kt) {
      int byte =
          (r0 + ln15) * 512 + ((kt * 64 + ln4 * 16) ^ ((ln15 & 7) << 4));
      ab[kt] = *(const short8*)((const char*)bn_lds + byte);
    }
#pragma unroll
    for (int nt = 0; nt < 16; ++nt) {
      int colc = nt * 16 + ln15;
      float bias = b_pc[colc];
      f32x4 acc = {bias, bias, bias, bias};
      const short8* bp = (const short8*)Wpc_pack + (nt * 8) * 64 + lane;
#pragma unroll
      for (int kt = 0; kt < 8; ++kt)
        acc = __builtin_amdgcn_mfma_f32_16x16x32_bf16(ab[kt], bp[kt * 64], acc,
                                                      0, 0, 0);
#pragma unroll
      for (int q = 0; q < 4; ++q)
        out_pc[(R0 + r0 + ln4 * 4 + q) * NPC + colc] = acc[q];
    }
    {
      int colc = ln15;
      float bias = (colc < NHD) ? b_hd[colc] : 0.0f;
      f32x4 acc = {bias, bias, bias, bias};
      const short8* bp = (const short8*)Whd_pack + lane;
#pragma unroll
      for (int kt = 0; kt < 8; ++kt)
        acc = __builtin_amdgcn_mfma_f32_16x16x32_bf16(ab[kt], bp[kt * 64], acc,
                                                      0, 0, 0);
      if (colc < NHD) {
#pragma unroll
        for (int q = 0; q < 4; ++q)
          out_hd[(R0 + r0 + ln4 * 4 + q) * NHD + colc] = acc[q];
      }
    }
  }
}

// ---------------------------------------------------------------------------
extern "C" void kernel_launch(void* const* d_in, const int* in_sizes, int n_in,
                              void* d_out, int out_size, void* d_ws,
                              size_t ws_size, hipStream_t stream) {
  (void)in_sizes;
  (void)n_in;
  (void)out_size;
  (void)ws_size;
  const float* x = (const float*)d_in[0];
  const float* init_pc = (const float*)d_in[1];
  const float* init_hd = (const float*)d_in[2];
  const float* Wz = (const float*)d_in[3];
  const float* Wr = (const float*)d_in[4];
  const float* Wh = (const float*)d_in[5];
  const float* Uz = (const float*)d_in[6];
  const float* Ur = (const float*)d_in[7];
  const float* Uh = (const float*)d_in[8];
  const float* bz = (const float*)d_in[9];
  const float* br = (const float*)d_in[10];
  const float* bh = (const float*)d_in[11];
  const float* W_embed = (const float*)d_in[12];
  const float* b_embed = (const float*)d_in[13];
  const float* W_bneck = (const float*)d_in[14];
  const float* W_pc = (const float*)d_in[15];
  const float* b_pc = (const float*)d_in[16];
  const float* W_hd = (const float*)d_in[17];
  const float* b_hd = (const float*)d_in[18];

  float* out = (float*)d_out;
  float* out_hd = out;
  float* out_pc = out_hd + (size_t)TT * BB * NHD;
  float* out_bn = out_pc + (size_t)TT * BB * NPC;
  float* out_st = out_bn + (size_t)TT * BB * NB;
  float* out_fs = out_st + (size_t)TT * BB * NU;

  float* h0 = (float*)d_ws;                            // 1 MB
  short* Wb_pack = (short*)((char*)d_ws + (1 << 20));  // 64 KB
  short* Wpc_pack = Wb_pack + 64 * 64 * 8;             // 128 KB
  short* Whd_pack = Wpc_pack + 128 * 64 * 8;           // 8 KB

  prepack_kernel<<<50, 256, 0, stream>>>(W_bneck, W_pc, W_hd, Wb_pack,
                                         Wpc_pack, Whd_pack);
  embed_kernel<<<BB / 2, 256, 0, stream>>>(init_pc, init_hd, W_embed, b_embed,
                                           h0);
  gru_mfma_kernel<<<BB / 8, 512, 0, stream>>>(x, h0, Wz, Wr, Wh, Uz, Ur, Uh,
                                              bz, br, bh, out_st, out_fs);
  heads_mfma_kernel<<<(TT * BB) / 64, 256, 0, stream>>>(
      out_st, Wb_pack, Wpc_pack, Whd_pack, b_pc, b_hd, out_hd, out_pc, out_bn);
}